// Round 5
// baseline (173.521 us; speedup 1.0000x reference)
//
#include <hip/hip_runtime.h>
#include <hip/hip_bf16.h>
#include <math.h>

// Problem constants
#define D_BINS 59
#define CTX    80
#define O_TOT  139
#define K_CIN  256
#define PIXELS 704
#define BNPAIR 24
#define BEVHW  16384
#define NBATCH 4

// BEV binning: tile = 8 rows x 16 cols -> 128 cells, 128 tiles/batch.
#define NTILE   128
#define NBUCKET (NBATCH * NTILE)   // 512
#define TCELLS  128

// producer blocks: 16 px per one-wave block; 24 bn * 44 ptiles * 2 roles.
#define PXT    16
#define NPXT   44                  // 704/16
#define NBLK   (BNPAIR * NPXT)     // 1056 regions
#define SEGS   (6 * NPXT)          // 264 segments per bucket
#define EPB    (PXT * D_BINS)      // 944 entries per region

#define CAP    2816
#define CAPP   (CAP + TCELLS * 7)  // 3712 (pad-to-8 worst slack)

// Workspace layout (4B units)
#define WHL_OFF      0
#define WHL_F        36864                         // 2 planes * 144*256 bf16
#define CTX_OFF      (WHL_OFF + WHL_F)
#define CTX_F        (BNPAIR * PIXELS * CTX / 2)   // 675,840
#define CNTMAT_OFF   (CTX_OFF + CTX_F)             // transposed [NTILE][NBLK]
#define OFSMAT_OFF   (CNTMAT_OFF + NTILE * NBLK)
#define CELLHIST_OFF (OFSMAT_OFF + NTILE * NBLK)   // [NBUCKET][TCELLS]
#define PLIST_OFF    (CELLHIST_OFF + NBUCKET * TCELLS)   // even -> uint2 ok

typedef __attribute__((ext_vector_type(8))) short bf16x8;
typedef __attribute__((ext_vector_type(4))) float f32x4;

__device__ __forceinline__ unsigned short f2bf(float v) {
    __hip_bfloat16 h = __float2bfloat16(v);   // RNE
    return *reinterpret_cast<unsigned short*>(&h);
}
__device__ __forceinline__ float bf2f(unsigned short u) {
    return __uint_as_float(((unsigned)u) << 16);
}

// ---------------------------------------------------------------------------
// Kernel 0 (wsplit): W -> bf16 hi/lo planes [144][256]; also zeroes the
// per-(bucket,cell) histogram the producer will atomically build.
// ---------------------------------------------------------------------------
__global__ __launch_bounds__(256) void wsplit_kernel(
    const float* __restrict__ w, unsigned short* __restrict__ whl,
    int* __restrict__ cellhist)
{
    const int row = blockIdx.x;        // 0..143
    const int col = threadIdx.x;       // 0..255
    const float v = (row < O_TOT) ? w[(size_t)row * K_CIN + col] : 0.f;
    const unsigned short hi = f2bf(v);
    const unsigned short lo = f2bf(v - bf2f(hi));
    whl[row * K_CIN + col]         = hi;
    whl[36864 + row * K_CIN + col] = lo;
    // zero cellhist (65,536 ints over 36,864 threads)
    const int zid = blockIdx.x * 256 + threadIdx.x;
    for (int i = zid; i < NBUCKET * TCELLS; i += 144 * 256) cellhist[i] = 0;
}

// ---------------------------------------------------------------------------
// K-loop: per-wave MFMA, operands straight from global (no LDS/barriers).
// Identical operand values + MFMA order to the r2/r4-verified kernels; adds
// explicit next-k img prefetch registers so HBM/L2 latency hides under the
// current k-step's convert+MFMA work.
// ---------------------------------------------------------------------------
template<int NT, int T0>
__device__ __forceinline__ void kloop(
    const float* __restrict__ ib, const unsigned short* __restrict__ whl,
    int pxg, int m, int g, f32x4* acc)
{
    const float* bp = ib + (size_t)(8 * g) * PIXELS + pxg;
    float bv[8];
#pragma unroll
    for (int j = 0; j < 8; ++j) bv[j] = bp[(size_t)j * PIXELS];
#pragma unroll
    for (int ks = 0; ks < 8; ++ks) {
        float bvn[8];
        if (ks < 7) {
#pragma unroll
            for (int j = 0; j < 8; ++j)
                bvn[j] = bp[(size_t)((ks + 1) * 32 + j) * PIXELS];
        }
        bf16x8 bhi, blo;
#pragma unroll
        for (int j = 0; j < 8; ++j) {
            const unsigned short h = f2bf(bv[j]);
            bhi[j] = (short)h;
            blo[j] = (short)f2bf(bv[j] - bf2f(h));
        }
#pragma unroll
        for (int t = 0; t < NT; ++t) {
            const int row = (T0 + t) * 16 + m;
            const bf16x8 ahi = *(const bf16x8*)&whl[(size_t)row * K_CIN + ks * 32 + g * 8];
            const bf16x8 alo = *(const bf16x8*)&whl[36864 + (size_t)row * K_CIN + ks * 32 + g * 8];
            acc[t] = __builtin_amdgcn_mfma_f32_16x16x32_bf16(ahi, bhi, acc[t], 0, 0, 0);
            acc[t] = __builtin_amdgcn_mfma_f32_16x16x32_bf16(ahi, blo, acc[t], 0, 0, 0);
            acc[t] = __builtin_amdgcn_mfma_f32_16x16x32_bf16(alo, bhi, acc[t], 0, 0, 0);
        }
        if (ks < 7) {
#pragma unroll
            for (int j = 0; j < 8; ++j) bv[j] = bvn[j];
        }
    }
}

// ---------------------------------------------------------------------------
// Kernel 1: one-wave blocks, zero __syncthreads. z=0: depth (tiles 0..3,
// softmax + binning + plist scatter + GLOBAL cell histogram). z=1: ctx.
// geom/bias loads hoisted above the k-loop (latency overlap).
// ---------------------------------------------------------------------------
__global__ __launch_bounds__(64) void gemm_fused(
    const float* __restrict__ img,            // (24, 256, 704)
    const unsigned short* __restrict__ whl,   // 2 planes [144][256] bf16 bits
    const float* __restrict__ bias,           // (139)
    const int*   __restrict__ geom,           // (24, 59, 704, 2)
    __hip_bfloat16* __restrict__ ctx,         // (24, 704, 80) bf16
    uint2*       __restrict__ plist,          // [NBLK][EPB]
    int*         __restrict__ cntmat_t,       // [NTILE][NBLK]
    int*         __restrict__ ofsmat_t,       // [NTILE][NBLK]
    int*         __restrict__ cellhist)       // [NBUCKET][TCELLS]
{
    const int lane = threadIdx.x;
    const int m    = lane & 15;
    const int g    = lane >> 4;                // == q for C-rows
    const int pt   = blockIdx.x;               // 0..43
    const int bn   = blockIdx.y;               // 0..23
    const int p0   = pt * PXT;
    const int pxg  = p0 + m;
    const int blkid = bn * NPXT + pt;
    const float* ib = img + (size_t)bn * K_CIN * PIXELS;

    if (blockIdx.z == 0) {
        // ================= depth role =================
        __shared__ int lh[NTILE], lofs[NTILE], lcur[NTILE];

        // hoisted loads: geom + bias issue before the K-loop
        const int2* g2 = (const int2*)geom;
        int2 gg[4][4];
        float4 bb[4];
#pragma unroll
        for (int t = 0; t < 4; ++t) {
            bb[t] = *(const float4*)&bias[16 * t + 4 * g];
#pragma unroll
            for (int r = 0; r < 4; ++r) {
                const int o = 16 * t + 4 * g + r;
                if (o < D_BINS)
                    gg[t][r] = g2[((size_t)(bn * D_BINS + o)) * PIXELS + pxg];
            }
        }
        lh[lane] = 0; lh[lane + 64] = 0;
        lcur[lane] = 0; lcur[lane + 64] = 0;

        f32x4 acc[4];
#pragma unroll
        for (int t = 0; t < 4; ++t) acc[t] = (f32x4){0.f, 0.f, 0.f, 0.f};
        kloop<4, 0>(ib, whl, pxg, m, g, acc);

        // bias
#pragma unroll
        for (int t = 0; t < 4; ++t) {
            acc[t][0] += bb[t].x; acc[t][1] += bb[t].y;
            acc[t][2] += bb[t].z; acc[t][3] += bb[t].w;
        }

        // softmax over o<59 (identical op order to verified kernels)
        float gm = -INFINITY;
#pragma unroll
        for (int t = 0; t < 4; ++t)
#pragma unroll
            for (int r = 0; r < 4; ++r)
                if (16 * t + 4 * g + r < D_BINS) gm = fmaxf(gm, acc[t][r]);
        gm = fmaxf(gm, __shfl_xor(gm, 16));
        gm = fmaxf(gm, __shfl_xor(gm, 32));
        float ls = 0.f;
#pragma unroll
        for (int t = 0; t < 4; ++t)
#pragma unroll
            for (int r = 0; r < 4; ++r)
                if (16 * t + 4 * g + r < D_BINS) {
                    const float e = __expf(acc[t][r] - gm);
                    acc[t][r] = e;
                    ls += e;
                }
        ls += __shfl_xor(ls, 16);
        ls += __shfl_xor(ls, 32);
        const float inv = 1.f / ls;

        // bucket/cell codes + wave-local tile histogram + GLOBAL cell hist
        const int bat = bn / 6;
        unsigned uc[4][4];
#pragma unroll
        for (int t = 0; t < 4; ++t)
#pragma unroll
            for (int r = 0; r < 4; ++r) {
                const int o = 16 * t + 4 * g + r;
                if (o < D_BINS) {
                    const int2 q = gg[t][r];
                    const int tile = (q.x >> 3) * 8 + (q.y >> 4);
                    const int cell = (q.x & 7) * 16 + (q.y & 15);
                    uc[t][r] = (unsigned)((tile << 7) | cell);
                    atomicAdd(&lh[tile], 1);
                    atomicAdd(&cellhist[(bat << 14) | uc[t][r]], 1);
                }
            }

        // in-wave scan of 128 tile counts: lane owns tiles 2l, 2l+1
        const int l2 = 2 * lane;
        const int a = lh[l2];
        const int b = lh[l2 + 1];
        const int p = a + b;
        int incl = p;
#pragma unroll
        for (int off = 1; off < 64; off <<= 1) {
            const int t = __shfl_up(incl, off);
            if (lane >= off) incl += t;
        }
        const int excl = incl - p;
        lofs[l2]     = excl;
        lofs[l2 + 1] = excl + a;
        cntmat_t[(size_t)l2 * NBLK + blkid]       = a;
        cntmat_t[(size_t)(l2 + 1) * NBLK + blkid] = b;
        ofsmat_t[(size_t)l2 * NBLK + blkid]       = excl;
        ofsmat_t[(size_t)(l2 + 1) * NBLK + blkid] = excl + a;

        // scatter this lane's own points
        uint2* dst = plist + (size_t)blkid * EPB;
        const unsigned ctxoff = (unsigned)((bn * PIXELS + pxg) * CTX);
#pragma unroll
        for (int t = 0; t < 4; ++t)
#pragma unroll
            for (int r = 0; r < 4; ++r) {
                const int o = 16 * t + 4 * g + r;
                if (o < D_BINS) {
                    const unsigned u = uc[t][r];
                    const int tl = (int)(u >> 7);
                    const int pos = lofs[tl] + atomicAdd(&lcur[tl], 1);
                    dst[pos] = make_uint2(__float_as_uint(acc[t][r] * inv),
                                          (ctxoff << 7) | (u & 127u));
                }
            }
    } else {
        // ================= ctx role =================
        __shared__ unsigned short sctx[PXT][CTX];   // 2.5 KB
        float4 bb[6];
#pragma unroll
        for (int t = 0; t < 6; ++t)
            bb[t] = *(const float4*)&bias[(3 + t) * 16 + 4 * g];

        f32x4 acc[6];
#pragma unroll
        for (int t = 0; t < 6; ++t) acc[t] = (f32x4){0.f, 0.f, 0.f, 0.f};
        kloop<6, 3>(ib, whl, pxg, m, g, acc);

#pragma unroll
        for (int t = 0; t < 6; ++t) {
            const float bvv[4] = {bb[t].x, bb[t].y, bb[t].z, bb[t].w};
#pragma unroll
            for (int r = 0; r < 4; ++r) {
                const int o = (3 + t) * 16 + 4 * g + r;      // 48..143
                const int c = o - D_BINS;                    // -11..84
                if (c >= 0 && c < CTX)
                    sctx[m][c] = f2bf(acc[t][r] + bvv[r]);
            }
        }
        // coalesced writeout (wave-local LDS, ordered via lgkmcnt)
        const char* sb = (const char*)sctx;
        char* gb = (char*)ctx + ((size_t)(bn * PIXELS) + p0) * CTX * 2;
#pragma unroll
        for (int i = lane; i < PXT * CTX * 2 / 16; i += 64)   // 160 chunks
            *(float4*)(gb + i * 16) = *(const float4*)(sb + i * 16);
    }
}

// ---------------------------------------------------------------------------
// Kernel 2 (gather): 4 barriers total. Coalesced transposed cnt/ofs loads;
// single-wave shfl scan of padded cell counts (hist precomputed by producer);
// copy places points cell-sorted directly into bufB (no bufA, no reorder).
// Accumulate/epilogue identical to the verified version.
// ---------------------------------------------------------------------------
__global__ __launch_bounds__(1024) void gather_kernel(
    const uint2* __restrict__ plist,
    const int*   __restrict__ cntmat_t,   // [NTILE][NBLK]
    const int*   __restrict__ ofsmat_t,   // [NTILE][NBLK]
    const int*   __restrict__ cellhist,   // [NBUCKET][TCELLS]
    const unsigned short* __restrict__ ctx,
    float*       __restrict__ out)
{
    __shared__ float sacc[CTX][TCELLS + 1];   // 41.3 KB
    __shared__ uint2 bufB[CAPP];              // 29.7 KB
    __shared__ int segcnt[SEGS], segofsG[SEGS];
    __shared__ int cellcnt[TCELLS], celloff[TCELLS], cellcur[TCELLS];
    __shared__ int sPadTotal;

    const int tid    = threadIdx.x;
    const int wv     = tid >> 6;
    const int lane   = tid & 63;
    const int bucket = blockIdx.x;
    const int b      = bucket >> 7;
    const int tile   = bucket & 127;
    const int blk0   = b * SEGS;

    // coalesced loads: segment counts/offsets (264) + cell counts (128)
    if (tid < SEGS) {
        segcnt[tid]  = cntmat_t[(size_t)tile * NBLK + blk0 + tid];
        segofsG[tid] = ofsmat_t[(size_t)tile * NBLK + blk0 + tid];
    }
    if (tid >= 512 && tid < 512 + TCELLS)
        cellcnt[tid - 512] = cellhist[(size_t)bucket * TCELLS + (tid - 512)];
    __syncthreads();

    // wave 1: shfl-scan of 128 PADDED cell counts (no barriers inside)
    if (wv == 1) {
        int carry = 0;
#pragma unroll
        for (int c = 0; c < 2; ++c) {
            const int i = c * 64 + lane;
            const int pv = (cellcnt[i] + 7) & ~7;
            int incl = pv;
#pragma unroll
            for (int off = 1; off < 64; off <<= 1) {
                const int t = __shfl_up(incl, off);
                if (lane >= off) incl += t;
            }
            celloff[i] = carry + incl - pv;
            cellcur[i] = 0;
            carry += __shfl(incl, 63);
        }
        if (lane == 0) sPadTotal = carry;
    }
    __syncthreads();
    const int padtotal = sPadTotal;

    if (padtotal <= CAPP) {
        // ---- fast path ----
        // zero only the pad slots (disjoint from placement slots -> no race)
        if (tid < TCELLS) {
            const int o = celloff[tid] + cellcnt[tid];
            const int e = celloff[tid] + ((cellcnt[tid] + 7) & ~7);
            for (int i = o; i < e; ++i) bufB[i] = make_uint2(0u, 0u);
        }
        // copy with direct cell-sorted placement: 8-lane subgroups
        {
            const int sub = lane >> 3;
            const int sl  = lane & 7;
            for (int sgi = wv * 8 + sub; sgi < SEGS; sgi += 128) {
                const int n = segcnt[sgi];
                if (!n) continue;
                const uint2* sp = plist + (size_t)(blk0 + sgi) * EPB + segofsG[sgi];
                for (int i = sl; i < n; i += 8) {
                    const uint2 e = sp[i];
                    const int c = (int)(e.y & 127u);
                    bufB[celloff[c] + atomicAdd(&cellcur[c], 1)] = e;
                }
            }
        }
        __syncthreads();

        // accumulate: wave wv owns cells c = wv, wv+16, ...; lane l<40 owns
        // channels (2l, 2l+1); 8-pt unrolled, one u32 (2xbf16) load per point.
        for (int c = wv; c < TCELLS; c += 16) {
            const int s0 = celloff[c];
            const int pc = (cellcnt[c] + 7) & ~7;
            float a0 = 0.f, a1 = 0.f;
            for (int i = 0; i < pc; i += 8) {
                uint2 e[8];
#pragma unroll
                for (int r = 0; r < 8; ++r) e[r] = bufB[s0 + i + r];
                if (lane < 40) {
                    unsigned u[8];
#pragma unroll
                    for (int r = 0; r < 8; ++r)
                        u[r] = *(const unsigned*)(ctx + (e[r].y >> 7) + 2 * lane);
#pragma unroll
                    for (int r = 0; r < 8; ++r) {
                        const float d  = __uint_as_float(e[r].x);
                        a0 += d * __uint_as_float(u[r] << 16);
                        a1 += d * __uint_as_float(u[r] & 0xffff0000u);
                    }
                }
            }
            if (lane < 40) {
                sacc[2 * lane][c]     = a0;
                sacc[2 * lane + 1][c] = a1;
            }
        }
    } else {
        // ---- overflow path (~30 sigma; correctness only) ----
        for (int i = tid; i < CTX * (TCELLS + 1); i += 1024)
            ((float*)sacc)[i] = 0.f;
        __syncthreads();
        for (int sgi = 0; sgi < SEGS; ++sgi) {
            const int n = segcnt[sgi];
            if (!n) continue;
            const uint2* sp = plist + (size_t)(blk0 + sgi) * EPB + segofsG[sgi];
            for (int i = 0; i < n; ++i) {
                const uint2 e = sp[i];
                const int c = (int)(e.y & 127u);
                if ((c & 15) == wv && lane < 40) {
                    const unsigned u = *(const unsigned*)(ctx + (e.y >> 7) + 2 * lane);
                    const float dep = __uint_as_float(e.x);
                    sacc[2 * lane][c]     += dep * __uint_as_float(u << 16);
                    sacc[2 * lane + 1][c] += dep * __uint_as_float(u & 0xffff0000u);
                }
            }
        }
    }
    __syncthreads();

    // epilogue: full 64B line writes to (B,C,H,W)
    const int tr = tile >> 3;
    const int tc = tile & 7;
    const int c0  = tid >> 4;
    const int col = tid & 15;
#pragma unroll
    for (int cc = c0; cc < CTX; cc += 64) {
#pragma unroll
        for (int r = 0; r < 8; ++r) {
            out[((size_t)(b * CTX + cc)) * BEVHW + (tr * 8 + r) * 128 + tc * 16 + col]
                = sacc[cc][r * 16 + col];
        }
    }
}

extern "C" void kernel_launch(void* const* d_in, const int* in_sizes, int n_in,
                              void* d_out, int out_size, void* d_ws, size_t ws_size,
                              hipStream_t stream)
{
    const float* img  = (const float*)d_in[0];
    const float* w    = (const float*)d_in[4];
    const float* bias = (const float*)d_in[5];
    const int*   geom = (const int*)d_in[6];
    float*       out  = (float*)d_out;

    float* ws = (float*)d_ws;
    unsigned short* whl = (unsigned short*)(ws + WHL_OFF);
    __hip_bfloat16* ctx = (__hip_bfloat16*)(ws + CTX_OFF);
    int*   cntmat_t = (int*)(ws + CNTMAT_OFF);
    int*   ofsmat_t = (int*)(ws + OFSMAT_OFF);
    int*   cellhist = (int*)(ws + CELLHIST_OFF);
    uint2* plist    = (uint2*)(ws + PLIST_OFF);

    // 0. W -> bf16 hi/lo planes (147 KB, L2-resident) + zero cellhist
    wsplit_kernel<<<144, 256, 0, stream>>>(w, whl, cellhist);

    // 1. barrier-free one-wave MFMA blocks: z=0 depth+binning+hist, z=1 ctx
    {
        dim3 grid(NPXT, BNPAIR, 2);   // 2112 blocks x 64 threads
        gemm_fused<<<grid, 64, 0, stream>>>(img, whl, bias, geom, ctx,
                                            plist, cntmat_t, ofsmat_t, cellhist);
    }

    // 2. 4-barrier gather: direct cell-sorted placement + accumulate
    gather_kernel<<<NBUCKET, 1024, 0, stream>>>(plist, cntmat_t, ofsmat_t,
                                                cellhist,
                                                (const unsigned short*)ctx, out);
}

// Round 6
// 140.884 us; speedup vs baseline: 1.2317x; 1.2317x over previous
//
#include <hip/hip_runtime.h>
#include <hip/hip_bf16.h>
#include <math.h>

// Problem constants
#define D_BINS 59
#define CTX    80
#define O_TOT  139
#define K_CIN  256
#define PIXELS 704
#define BNPAIR 24
#define BEVHW  16384
#define NBATCH 4

// BEV binning: tile = 8 rows x 16 cols -> 128 cells, 128 tiles/batch.
#define NTILE   128
#define NBUCKET (NBATCH * NTILE)   // 512
#define TCELLS  128

// producer blocks: 16 px per one-wave block; 24 bn * 44 ptiles * 2 roles.
#define PXT    16
#define NPXT   44                  // 704/16
#define NBLK   (BNPAIR * NPXT)     // 1056 regions
#define SEGS   (6 * NPXT)          // 264 segments per bucket
#define EPB    (PXT * D_BINS)      // 944 entries per region

#define CAP    2816
#define CAPP   (CAP + TCELLS * 7)  // 3712; padtotal <= CAPP always holds

// Workspace layout (4B units)
#define WHL_OFF      0
#define WHL_F        36864                         // 2 planes * 144*256 bf16
#define CTX_OFF      (WHL_OFF + WHL_F)
#define CTX_F        (BNPAIR * PIXELS * CTX / 2)   // 675,840
#define CNTMAT_OFF   (CTX_OFF + CTX_F)             // transposed [NTILE][NBLK]
#define OFSMAT_OFF   (CNTMAT_OFF + NTILE * NBLK)
#define PLIST_OFF    (OFSMAT_OFF + NTILE * NBLK)   // even -> uint2 aligned

typedef __attribute__((ext_vector_type(8))) short bf16x8;
typedef __attribute__((ext_vector_type(4))) float f32x4;

__device__ __forceinline__ unsigned short f2bf(float v) {
    __hip_bfloat16 h = __float2bfloat16(v);   // RNE
    return *reinterpret_cast<unsigned short*>(&h);
}
__device__ __forceinline__ float bf2f(unsigned short u) {
    return __uint_as_float(((unsigned)u) << 16);
}

// ---------------------------------------------------------------------------
// Kernel 0 (wsplit): W -> bf16 hi/lo planes [144][256], pad=0.
// ---------------------------------------------------------------------------
__global__ __launch_bounds__(256) void wsplit_kernel(
    const float* __restrict__ w, unsigned short* __restrict__ whl)
{
    const int row = blockIdx.x;        // 0..143
    const int col = threadIdx.x;       // 0..255
    const float v = (row < O_TOT) ? w[(size_t)row * K_CIN + col] : 0.f;
    const unsigned short hi = f2bf(v);
    const unsigned short lo = f2bf(v - bf2f(hi));
    whl[row * K_CIN + col]         = hi;
    whl[36864 + row * K_CIN + col] = lo;
}

// ---------------------------------------------------------------------------
// K-loop: per-wave MFMA, operands straight from global (no LDS/barriers).
// EXACT r4 form (measured good): unroll-2, compiler-scheduled loads.
// MFMA order (ahi,bhi),(ahi,blo),(alo,bhi) -> bitwise == verified numerics.
// ---------------------------------------------------------------------------
template<int NT, int T0>
__device__ __forceinline__ void kloop(
    const float* __restrict__ ib, const unsigned short* __restrict__ whl,
    int pxg, int m, int g, f32x4* acc)
{
#pragma unroll 2
    for (int ks = 0; ks < 8; ++ks) {
        float bv[8];
#pragma unroll
        for (int j = 0; j < 8; ++j)
            bv[j] = ib[(size_t)(ks * 32 + 8 * g + j) * PIXELS + pxg];
        bf16x8 bhi, blo;
#pragma unroll
        for (int j = 0; j < 8; ++j) {
            const unsigned short h = f2bf(bv[j]);
            bhi[j] = (short)h;
            blo[j] = (short)f2bf(bv[j] - bf2f(h));
        }
#pragma unroll
        for (int t = 0; t < NT; ++t) {
            const int row = (T0 + t) * 16 + m;
            const bf16x8 ahi = *(const bf16x8*)&whl[(size_t)row * K_CIN + ks * 32 + g * 8];
            const bf16x8 alo = *(const bf16x8*)&whl[36864 + (size_t)row * K_CIN + ks * 32 + g * 8];
            acc[t] = __builtin_amdgcn_mfma_f32_16x16x32_bf16(ahi, bhi, acc[t], 0, 0, 0);
            acc[t] = __builtin_amdgcn_mfma_f32_16x16x32_bf16(ahi, blo, acc[t], 0, 0, 0);
            acc[t] = __builtin_amdgcn_mfma_f32_16x16x32_bf16(alo, bhi, acc[t], 0, 0, 0);
        }
    }
}

// ---------------------------------------------------------------------------
// Kernel 1: one-wave blocks, zero __syncthreads (r4-exact structure; only
// change: cnt/ofs stored transposed so gather reads coalesce). NO global
// atomics (r5's cellhist atomics caused 50 MB of cross-XCD RMW traffic).
// ---------------------------------------------------------------------------
__global__ __launch_bounds__(64) void gemm_fused(
    const float* __restrict__ img,            // (24, 256, 704)
    const unsigned short* __restrict__ whl,   // 2 planes [144][256] bf16 bits
    const float* __restrict__ bias,           // (139)
    const int*   __restrict__ geom,           // (24, 59, 704, 2)
    __hip_bfloat16* __restrict__ ctx,         // (24, 704, 80) bf16
    uint2*       __restrict__ plist,          // [NBLK][EPB]
    int*         __restrict__ cntmat_t,       // [NTILE][NBLK]
    int*         __restrict__ ofsmat_t)       // [NTILE][NBLK]
{
    const int lane = threadIdx.x;
    const int m    = lane & 15;
    const int g    = lane >> 4;                // == q for C-rows
    const int pt   = blockIdx.x;               // 0..43
    const int bn   = blockIdx.y;               // 0..23
    const int p0   = pt * PXT;
    const int pxg  = p0 + m;
    const int blkid = bn * NPXT + pt;
    const float* ib = img + (size_t)bn * K_CIN * PIXELS;

    if (blockIdx.z == 0) {
        // ================= depth role =================
        __shared__ int lh[NTILE], lofs[NTILE], lcur[NTILE];
        f32x4 acc[4];
#pragma unroll
        for (int t = 0; t < 4; ++t) acc[t] = (f32x4){0.f, 0.f, 0.f, 0.f};
        kloop<4, 0>(ib, whl, pxg, m, g, acc);

        // geom loads issued before the softmax chain (latency overlap)
        const int2* g2 = (const int2*)geom;
        int2 gg[4][4];
#pragma unroll
        for (int t = 0; t < 4; ++t)
#pragma unroll
            for (int r = 0; r < 4; ++r) {
                const int o = 16 * t + 4 * g + r;
                if (o < D_BINS)
                    gg[t][r] = g2[((size_t)(bn * D_BINS + o)) * PIXELS + pxg];
            }
        lh[lane] = 0; lh[lane + 64] = 0;
        lcur[lane] = 0; lcur[lane + 64] = 0;

        // bias (rows 0..63 all < 139)
#pragma unroll
        for (int t = 0; t < 4; ++t)
#pragma unroll
            for (int r = 0; r < 4; ++r) acc[t][r] += bias[16 * t + 4 * g + r];

        // softmax over o<59 (identical op order to verified kernels)
        float gm = -INFINITY;
#pragma unroll
        for (int t = 0; t < 4; ++t)
#pragma unroll
            for (int r = 0; r < 4; ++r)
                if (16 * t + 4 * g + r < D_BINS) gm = fmaxf(gm, acc[t][r]);
        gm = fmaxf(gm, __shfl_xor(gm, 16));
        gm = fmaxf(gm, __shfl_xor(gm, 32));
        float ls = 0.f;
#pragma unroll
        for (int t = 0; t < 4; ++t)
#pragma unroll
            for (int r = 0; r < 4; ++r)
                if (16 * t + 4 * g + r < D_BINS) {
                    const float e = __expf(acc[t][r] - gm);
                    acc[t][r] = e;
                    ls += e;
                }
        ls += __shfl_xor(ls, 16);
        ls += __shfl_xor(ls, 32);
        const float inv = 1.f / ls;

        // bucket/cell codes + wave-local histogram (LDS atomics, no barrier)
        unsigned uc[4][4];
#pragma unroll
        for (int t = 0; t < 4; ++t)
#pragma unroll
            for (int r = 0; r < 4; ++r) {
                const int o = 16 * t + 4 * g + r;
                if (o < D_BINS) {
                    const int2 q = gg[t][r];
                    const int tile = (q.x >> 3) * 8 + (q.y >> 4);
                    const int cell = (q.x & 7) * 16 + (q.y & 15);
                    uc[t][r] = (unsigned)((tile << 7) | cell);
                    atomicAdd(&lh[tile], 1);
                }
            }

        // in-wave scan of 128 tile counts: lane owns tiles 2l, 2l+1
        const int l2 = 2 * lane;
        const int a = lh[l2];
        const int b = lh[l2 + 1];
        const int p = a + b;
        int incl = p;
#pragma unroll
        for (int off = 1; off < 64; off <<= 1) {
            const int t = __shfl_up(incl, off);
            if (lane >= off) incl += t;
        }
        const int excl = incl - p;
        lofs[l2]     = excl;
        lofs[l2 + 1] = excl + a;
        cntmat_t[(size_t)l2 * NBLK + blkid]       = a;
        cntmat_t[(size_t)(l2 + 1) * NBLK + blkid] = b;
        ofsmat_t[(size_t)l2 * NBLK + blkid]       = excl;
        ofsmat_t[(size_t)(l2 + 1) * NBLK + blkid] = excl + a;

        // scatter this lane's own points
        uint2* dst = plist + (size_t)blkid * EPB;
        const unsigned ctxoff = (unsigned)((bn * PIXELS + pxg) * CTX);
#pragma unroll
        for (int t = 0; t < 4; ++t)
#pragma unroll
            for (int r = 0; r < 4; ++r) {
                const int o = 16 * t + 4 * g + r;
                if (o < D_BINS) {
                    const unsigned u = uc[t][r];
                    const int tl = (int)(u >> 7);
                    const int pos = lofs[tl] + atomicAdd(&lcur[tl], 1);
                    dst[pos] = make_uint2(__float_as_uint(acc[t][r] * inv),
                                          (ctxoff << 7) | (u & 127u));
                }
            }
    } else {
        // ================= ctx role =================
        __shared__ unsigned short sctx[PXT][CTX];   // 2.5 KB
        f32x4 acc[6];
#pragma unroll
        for (int t = 0; t < 6; ++t) acc[t] = (f32x4){0.f, 0.f, 0.f, 0.f};
        kloop<6, 3>(ib, whl, pxg, m, g, acc);

#pragma unroll
        for (int t = 0; t < 6; ++t)
#pragma unroll
            for (int r = 0; r < 4; ++r) {
                const int o = (3 + t) * 16 + 4 * g + r;      // 48..143
                const int c = o - D_BINS;                    // -11..84
                if (c >= 0 && c < CTX)
                    sctx[m][c] = f2bf(acc[t][r] + bias[o]);
            }
        // coalesced writeout (wave-local LDS, ordered via lgkmcnt)
        const char* sb = (const char*)sctx;
        char* gb = (char*)ctx + ((size_t)(bn * PIXELS) + p0) * CTX * 2;
#pragma unroll
        for (int i = lane; i < PXT * CTX * 2 / 16; i += 64)   // 160 chunks
            *(float4*)(gb + i * 16) = *(const float4*)(sb + i * 16);
    }
}

// ---------------------------------------------------------------------------
// Kernel 2 (gather): 6 barriers. Coalesced transposed cnt/ofs loads; both
// scans are single-wave shfl scans; cell histogram built in LDS DURING the
// copy pass (fused, not a separate sweep); one reorder bufA -> bufB.
// Accumulate/epilogue identical to the verified r4 version.
// ---------------------------------------------------------------------------
__global__ __launch_bounds__(1024) void gather_kernel(
    const uint2* __restrict__ plist,
    const int*   __restrict__ cntmat_t,   // [NTILE][NBLK]
    const int*   __restrict__ ofsmat_t,   // [NTILE][NBLK]
    const unsigned short* __restrict__ ctx,
    float*       __restrict__ out)
{
    __shared__ float sacc[CTX][TCELLS + 1];   // 41.3 KB
    __shared__ uint2 bufB[CAPP];              // 29.7 KB
    __shared__ int segcnt[SEGS], segofsL[SEGS], segofsG[SEGS];
    __shared__ int cellcnt[TCELLS], celloff[TCELLS], cellcur[TCELLS];
    __shared__ int sTotal;
    uint2* bufA = (uint2*)sacc;               // overlay: bufA dead once sacc live

    const int tid    = threadIdx.x;
    const int wv     = tid >> 6;
    const int lane   = tid & 63;
    const int bucket = blockIdx.x;
    const int b      = bucket >> 7;
    const int tile   = bucket & 127;
    const int blk0   = b * SEGS;

    // phase 1: coalesced metadata loads + cellcnt zero
    if (tid < SEGS) {
        segcnt[tid]  = cntmat_t[(size_t)tile * NBLK + blk0 + tid];
        segofsG[tid] = ofsmat_t[(size_t)tile * NBLK + blk0 + tid];
    }
    if (tid >= 512 && tid < 512 + TCELLS) cellcnt[tid - 512] = 0;
    __syncthreads();

    // phase 2: wave 0 shfl-scans the 264 segment counts (5 chunks, carry)
    if (wv == 0) {
        int carry = 0;
#pragma unroll
        for (int c = 0; c < 5; ++c) {
            const int i = c * 64 + lane;
            const int v = (i < SEGS) ? segcnt[i] : 0;
            int incl = v;
#pragma unroll
            for (int off = 1; off < 64; off <<= 1) {
                const int t = __shfl_up(incl, off);
                if (lane >= off) incl += t;
            }
            if (i < SEGS) segofsL[i] = carry + incl - v;
            carry += __shfl(incl, 63);
        }
        if (lane == 0) sTotal = carry;
    }
    __syncthreads();
    const int total = sTotal;
    const int ncap  = (total < CAP) ? total : CAP;

    // phase 3: copy segments -> bufA AND build LDS cell histogram (fused)
    {
        const int sub = lane >> 3;
        const int sl  = lane & 7;
        for (int sgi = wv * 8 + sub; sgi < SEGS; sgi += 128) {
            const int n = segcnt[sgi];
            if (!n) continue;
            const int dstb = segofsL[sgi];
            const uint2* sp = plist + (size_t)(blk0 + sgi) * EPB + segofsG[sgi];
            for (int i = sl; i < n; i += 8) {
                const int d = dstb + i;
                if (d < CAP) {
                    const uint2 e = sp[i];
                    bufA[d] = e;
                    atomicAdd(&cellcnt[e.y & 127u], 1);
                }
            }
        }
    }
    __syncthreads();

    // phase 4: wave 1 shfl-scans the 128 PADDED cell counts
    if (wv == 1) {
        int carry = 0;
#pragma unroll
        for (int c = 0; c < 2; ++c) {
            const int i = c * 64 + lane;
            const int pv = (cellcnt[i] + 7) & ~7;
            int incl = pv;
#pragma unroll
            for (int off = 1; off < 64; off <<= 1) {
                const int t = __shfl_up(incl, off);
                if (lane >= off) incl += t;
            }
            celloff[i] = carry + incl - pv;
            cellcur[i] = 0;
            carry += __shfl(incl, 63);
        }
    }
    __syncthreads();

    // phase 5: zero pad slots (disjoint) + reorder bufA -> bufB cell-sorted
    if (tid < TCELLS) {
        const int o = celloff[tid] + cellcnt[tid];
        const int e = celloff[tid] + ((cellcnt[tid] + 7) & ~7);
        for (int i = o; i < e; ++i) bufB[i] = make_uint2(0u, 0u);
    }
    for (int i = tid; i < ncap; i += 1024) {
        const uint2 e = bufA[i];
        const int c = (int)(e.y & 127u);
        bufB[celloff[c] + atomicAdd(&cellcur[c], 1)] = e;
    }
    __syncthreads();   // bufA dead; sacc live from here

    // accumulate: wave wv owns cells c = wv, wv+16, ...; lane l<40 owns
    // channels (2l, 2l+1); 8-pt unrolled, one u32 (2xbf16) load per point.
    for (int c = wv; c < TCELLS; c += 16) {
        const int s0 = celloff[c];
        const int pc = (cellcnt[c] + 7) & ~7;
        float a0 = 0.f, a1 = 0.f;
        for (int i = 0; i < pc; i += 8) {
            uint2 e[8];
#pragma unroll
            for (int r = 0; r < 8; ++r) e[r] = bufB[s0 + i + r];
            if (lane < 40) {
                unsigned u[8];
#pragma unroll
                for (int r = 0; r < 8; ++r)
                    u[r] = *(const unsigned*)(ctx + (e[r].y >> 7) + 2 * lane);
#pragma unroll
                for (int r = 0; r < 8; ++r) {
                    const float d  = __uint_as_float(e[r].x);
                    a0 += d * __uint_as_float(u[r] << 16);
                    a1 += d * __uint_as_float(u[r] & 0xffff0000u);
                }
            }
        }
        if (lane < 40) {
            sacc[2 * lane][c]     = a0;
            sacc[2 * lane + 1][c] = a1;
        }
    }

    // slow path for bucket overflow (~30 sigma; correctness only)
    if (total > CAP) {
        for (int sgi = 0; sgi < SEGS; ++sgi) {
            const int dstb = segofsL[sgi];
            const int n    = segcnt[sgi];
            if (dstb + n <= CAP) continue;
            const uint2* sp = plist + (size_t)(blk0 + sgi) * EPB + segofsG[sgi];
            const int i0 = (CAP > dstb) ? (CAP - dstb) : 0;
            for (int i = i0; i < n; ++i) {
                const uint2 e = sp[i];
                const int c = (int)(e.y & 127u);
                if ((c & 15) == wv && lane < 40) {
                    const unsigned u = *(const unsigned*)(ctx + (e.y >> 7) + 2 * lane);
                    const float dep = __uint_as_float(e.x);
                    sacc[2 * lane][c]     += dep * __uint_as_float(u << 16);
                    sacc[2 * lane + 1][c] += dep * __uint_as_float(u & 0xffff0000u);
                }
            }
        }
    }
    __syncthreads();

    // epilogue: full 64B line writes to (B,C,H,W)
    const int tr = tile >> 3;
    const int tc = tile & 7;
    const int c0  = tid >> 4;
    const int col = tid & 15;
#pragma unroll
    for (int cc = c0; cc < CTX; cc += 64) {
#pragma unroll
        for (int r = 0; r < 8; ++r) {
            out[((size_t)(b * CTX + cc)) * BEVHW + (tr * 8 + r) * 128 + tc * 16 + col]
                = sacc[cc][r * 16 + col];
        }
    }
}

extern "C" void kernel_launch(void* const* d_in, const int* in_sizes, int n_in,
                              void* d_out, int out_size, void* d_ws, size_t ws_size,
                              hipStream_t stream)
{
    const float* img  = (const float*)d_in[0];
    const float* w    = (const float*)d_in[4];
    const float* bias = (const float*)d_in[5];
    const int*   geom = (const int*)d_in[6];
    float*       out  = (float*)d_out;

    float* ws = (float*)d_ws;
    unsigned short* whl = (unsigned short*)(ws + WHL_OFF);
    __hip_bfloat16* ctx = (__hip_bfloat16*)(ws + CTX_OFF);
    int*   cntmat_t = (int*)(ws + CNTMAT_OFF);
    int*   ofsmat_t = (int*)(ws + OFSMAT_OFF);
    uint2* plist    = (uint2*)(ws + PLIST_OFF);

    // 0. W -> bf16 hi/lo planes (147 KB, L2-resident)
    wsplit_kernel<<<144, 256, 0, stream>>>(w, whl);

    // 1. barrier-free one-wave MFMA blocks: z=0 depth+binning, z=1 ctx
    {
        dim3 grid(NPXT, BNPAIR, 2);   // 2112 blocks x 64 threads
        gemm_fused<<<grid, 64, 0, stream>>>(img, whl, bias, geom, ctx,
                                            plist, cntmat_t, ofsmat_t);
    }

    // 2. 6-barrier gather: fused copy+hist, shfl scans, reorder, accumulate
    gather_kernel<<<NBUCKET, 1024, 0, stream>>>(plist, cntmat_t, ofsmat_t,
                                                (const unsigned short*)ctx, out);
}

// Round 7
// 138.744 us; speedup vs baseline: 1.2507x; 1.0154x over previous
//
#include <hip/hip_runtime.h>
#include <hip/hip_bf16.h>
#include <math.h>

// Problem constants
#define D_BINS 59
#define CTX    80
#define O_TOT  139
#define K_CIN  256
#define PIXELS 704
#define BNPAIR 24
#define BEVHW  16384
#define NBATCH 4

// BEV binning: tile = 8 rows x 16 cols -> 128 cells, 128 tiles/batch.
#define NTILE   128
#define NBUCKET (NBATCH * NTILE)   // 512
#define TCELLS  128

// producer blocks: 16 px per one-wave block; 24 bn * 44 ptiles * 2 roles.
#define PXT    16
#define NPXT   44                  // 704/16
#define NBLK   (BNPAIR * NPXT)     // 1056 regions
#define SEGS   (6 * NPXT)          // 264 segments per bucket
#define EPB    (PXT * D_BINS)      // 944 entries per region

#define CAP    2816
#define CAPP   (CAP + TCELLS * 7)  // 3712; padtotal <= CAPP always holds

// Fragment slabs (bf16, fragment-major: every k-loop load is 64 lanes x 16B
// fully coalesced):
//   W frags:   [9 t][8 ks][2 pl][64 lane][8 ush] = 73,728 ush = 147 KB
//   img frags: [1056 blk][8 ks][2 pl][64 lane][8 ush] = 16 KB/blk = 16.5 MB
// Workspace layout (4B units)
#define WHLF_OFF   0
#define WHLF_F     36864
#define IMGF_OFF   (WHLF_OFF + WHLF_F)
#define IMGF_F     (NBLK * 4096)                   // 4,325,376
#define CTX_OFF    (IMGF_OFF + IMGF_F)
#define CTX_F      (BNPAIR * PIXELS * CTX / 2)     // 675,840
#define CNTMAT_OFF (CTX_OFF + CTX_F)               // transposed [NTILE][NBLK]
#define OFSMAT_OFF (CNTMAT_OFF + NTILE * NBLK)
#define PLIST_OFF  (OFSMAT_OFF + NTILE * NBLK)     // even -> uint2 aligned

typedef __attribute__((ext_vector_type(8))) short bf16x8;
typedef __attribute__((ext_vector_type(4))) float f32x4;

__device__ __forceinline__ unsigned short f2bf(float v) {
    __hip_bfloat16 h = __float2bfloat16(v);   // RNE
    return *reinterpret_cast<unsigned short*>(&h);
}
__device__ __forceinline__ float bf2f(unsigned short u) {
    return __uint_as_float(((unsigned)u) << 16);
}

// ---------------------------------------------------------------------------
// Kernel 0 (prep): fragment-major pre-conversion. Blocks x<44: img slab of
// (bn, pt) -> bf16 hi/lo fragments via 16 KB LDS stage (coalesced in, linear
// 16B-chunk copy out). Blocks x==44: W -> fragment-major hi/lo (6 rows each).
// Same f2bf splits as all verified rounds -> operand values bitwise identical.
// ---------------------------------------------------------------------------
__global__ __launch_bounds__(256) void prep_kernel(
    const float* __restrict__ img,            // (24, 256, 704)
    const float* __restrict__ w,              // (139, 256)
    unsigned short* __restrict__ wf,          // [9*8][2][512] ush
    unsigned short* __restrict__ imgf)        // [1056][8][2][512] ush
{
    const int tid = threadIdx.x;
    if (blockIdx.x == NPXT) {
        // ---- W role: 24 blocks (y=bn), 6 rows each ----
#pragma unroll
        for (int i = 0; i < 6; ++i) {
            const int row = blockIdx.y * 6 + i;     // 0..143
            const int col = tid;                    // 0..255
            const float v = (row < O_TOT) ? w[(size_t)row * K_CIN + col] : 0.f;
            const unsigned short hi = f2bf(v);
            const unsigned short lo = f2bf(v - bf2f(hi));
            const int t = row >> 4, m = row & 15;
            const int ks = col >> 5, kk = col & 31;
            const int g = kk >> 3, e = kk & 7;
            const size_t base = (size_t)(t * 8 + ks) * 1024 + (g * 16 + m) * 8 + e;
            wf[base]       = hi;
            wf[base + 512] = lo;
        }
        return;
    }
    // ---- img role ----
    __shared__ unsigned short sf[8192];   // 16 KB: [ks][pl][512]
    const int pt = blockIdx.x, bn = blockIdx.y;
    const int blk = bn * NPXT + pt;
    const float* ib = img + (size_t)bn * K_CIN * PIXELS + pt * PXT;
#pragma unroll
    for (int half = 0; half < 2; ++half) {
        const int eid = half * 256 + tid;          // 0..511
        const int kk = eid >> 4, px = eid & 15;    // kk 0..31
#pragma unroll
        for (int ks = 0; ks < 8; ++ks) {
            const float v = ib[(size_t)(ks * 32 + kk) * PIXELS + px];
            const unsigned short hi = f2bf(v);
            const unsigned short lo = f2bf(v - bf2f(hi));
            const int g = kk >> 3, e = kk & 7;
            sf[ks * 1024 + (g * 16 + px) * 8 + e]       = hi;
            sf[ks * 1024 + 512 + (g * 16 + px) * 8 + e] = lo;
        }
    }
    __syncthreads();
    uint2* ob = (uint2*)(imgf + (size_t)blk * 8192);
    const uint2* sb = (const uint2*)sf;
#pragma unroll
    for (int i = 0; i < 8; ++i)
        ob[tid + 256 * i] = sb[tid + 256 * i];
}

// ---------------------------------------------------------------------------
// K-loop: per-wave MFMA; EVERY load is 64 lanes x 16 B contiguous (1024 B
// per instruction) from the fragment slabs. Zero conversion VALU in-loop.
// MFMA order (ahi,bhi),(ahi,blo),(alo,bhi) == verified numerics.
// ---------------------------------------------------------------------------
template<int NT, int T0>
__device__ __forceinline__ void kloop(
    const unsigned short* __restrict__ ifr,   // this block's img frag base
    const unsigned short* __restrict__ wf,
    int lane, f32x4* acc)
{
#pragma unroll 2
    for (int ks = 0; ks < 8; ++ks) {
        const bf16x8 bhi = *(const bf16x8*)&ifr[ks * 1024 + lane * 8];
        const bf16x8 blo = *(const bf16x8*)&ifr[ks * 1024 + 512 + lane * 8];
#pragma unroll
        for (int t = 0; t < NT; ++t) {
            const size_t ab = (size_t)((T0 + t) * 8 + ks) * 1024 + lane * 8;
            const bf16x8 ahi = *(const bf16x8*)&wf[ab];
            const bf16x8 alo = *(const bf16x8*)&wf[ab + 512];
            acc[t] = __builtin_amdgcn_mfma_f32_16x16x32_bf16(ahi, bhi, acc[t], 0, 0, 0);
            acc[t] = __builtin_amdgcn_mfma_f32_16x16x32_bf16(ahi, blo, acc[t], 0, 0, 0);
            acc[t] = __builtin_amdgcn_mfma_f32_16x16x32_bf16(alo, bhi, acc[t], 0, 0, 0);
        }
    }
}

// ---------------------------------------------------------------------------
// Kernel 1: one-wave blocks, zero __syncthreads (r6-exact structure; only
// the operand sourcing changed to fragment slabs). No global atomics.
// ---------------------------------------------------------------------------
__global__ __launch_bounds__(64) void gemm_fused(
    const unsigned short* __restrict__ imgf,  // [1056][8192] ush
    const unsigned short* __restrict__ wf,    // [72][1024] ush
    const float* __restrict__ bias,           // (139)
    const int*   __restrict__ geom,           // (24, 59, 704, 2)
    __hip_bfloat16* __restrict__ ctx,         // (24, 704, 80) bf16
    uint2*       __restrict__ plist,          // [NBLK][EPB]
    int*         __restrict__ cntmat_t,       // [NTILE][NBLK]
    int*         __restrict__ ofsmat_t)       // [NTILE][NBLK]
{
    const int lane = threadIdx.x;
    const int m    = lane & 15;
    const int g    = lane >> 4;                // == q for C-rows
    const int pt   = blockIdx.x;               // 0..43
    const int bn   = blockIdx.y;               // 0..23
    const int p0   = pt * PXT;
    const int pxg  = p0 + m;
    const int blkid = bn * NPXT + pt;
    const unsigned short* ifr = imgf + (size_t)blkid * 8192;

    if (blockIdx.z == 0) {
        // ================= depth role =================
        __shared__ int lh[NTILE], lofs[NTILE], lcur[NTILE];
        f32x4 acc[4];
#pragma unroll
        for (int t = 0; t < 4; ++t) acc[t] = (f32x4){0.f, 0.f, 0.f, 0.f};
        kloop<4, 0>(ifr, wf, lane, acc);

        // geom loads issued before the softmax chain (latency overlap)
        const int2* g2 = (const int2*)geom;
        int2 gg[4][4];
#pragma unroll
        for (int t = 0; t < 4; ++t)
#pragma unroll
            for (int r = 0; r < 4; ++r) {
                const int o = 16 * t + 4 * g + r;
                if (o < D_BINS)
                    gg[t][r] = g2[((size_t)(bn * D_BINS + o)) * PIXELS + pxg];
            }
        lh[lane] = 0; lh[lane + 64] = 0;
        lcur[lane] = 0; lcur[lane + 64] = 0;

        // bias (rows 0..63 all < 139)
#pragma unroll
        for (int t = 0; t < 4; ++t)
#pragma unroll
            for (int r = 0; r < 4; ++r) acc[t][r] += bias[16 * t + 4 * g + r];

        // softmax over o<59 (identical op order to verified kernels)
        float gm = -INFINITY;
#pragma unroll
        for (int t = 0; t < 4; ++t)
#pragma unroll
            for (int r = 0; r < 4; ++r)
                if (16 * t + 4 * g + r < D_BINS) gm = fmaxf(gm, acc[t][r]);
        gm = fmaxf(gm, __shfl_xor(gm, 16));
        gm = fmaxf(gm, __shfl_xor(gm, 32));
        float ls = 0.f;
#pragma unroll
        for (int t = 0; t < 4; ++t)
#pragma unroll
            for (int r = 0; r < 4; ++r)
                if (16 * t + 4 * g + r < D_BINS) {
                    const float e = __expf(acc[t][r] - gm);
                    acc[t][r] = e;
                    ls += e;
                }
        ls += __shfl_xor(ls, 16);
        ls += __shfl_xor(ls, 32);
        const float inv = 1.f / ls;

        // bucket/cell codes + wave-local histogram (LDS atomics, no barrier)
        unsigned uc[4][4];
#pragma unroll
        for (int t = 0; t < 4; ++t)
#pragma unroll
            for (int r = 0; r < 4; ++r) {
                const int o = 16 * t + 4 * g + r;
                if (o < D_BINS) {
                    const int2 q = gg[t][r];
                    const int tile = (q.x >> 3) * 8 + (q.y >> 4);
                    const int cell = (q.x & 7) * 16 + (q.y & 15);
                    uc[t][r] = (unsigned)((tile << 7) | cell);
                    atomicAdd(&lh[tile], 1);
                }
            }

        // in-wave scan of 128 tile counts: lane owns tiles 2l, 2l+1
        const int l2 = 2 * lane;
        const int a = lh[l2];
        const int b = lh[l2 + 1];
        const int p = a + b;
        int incl = p;
#pragma unroll
        for (int off = 1; off < 64; off <<= 1) {
            const int t = __shfl_up(incl, off);
            if (lane >= off) incl += t;
        }
        const int excl = incl - p;
        lofs[l2]     = excl;
        lofs[l2 + 1] = excl + a;
        cntmat_t[(size_t)l2 * NBLK + blkid]       = a;
        cntmat_t[(size_t)(l2 + 1) * NBLK + blkid] = b;
        ofsmat_t[(size_t)l2 * NBLK + blkid]       = excl;
        ofsmat_t[(size_t)(l2 + 1) * NBLK + blkid] = excl + a;

        // scatter this lane's own points
        uint2* dst = plist + (size_t)blkid * EPB;
        const unsigned ctxoff = (unsigned)((bn * PIXELS + pxg) * CTX);
#pragma unroll
        for (int t = 0; t < 4; ++t)
#pragma unroll
            for (int r = 0; r < 4; ++r) {
                const int o = 16 * t + 4 * g + r;
                if (o < D_BINS) {
                    const unsigned u = uc[t][r];
                    const int tl = (int)(u >> 7);
                    const int pos = lofs[tl] + atomicAdd(&lcur[tl], 1);
                    dst[pos] = make_uint2(__float_as_uint(acc[t][r] * inv),
                                          (ctxoff << 7) | (u & 127u));
                }
            }
    } else {
        // ================= ctx role =================
        __shared__ unsigned short sctx[PXT][CTX];   // 2.5 KB
        f32x4 acc[6];
#pragma unroll
        for (int t = 0; t < 6; ++t) acc[t] = (f32x4){0.f, 0.f, 0.f, 0.f};
        kloop<6, 3>(ifr, wf, lane, acc);

#pragma unroll
        for (int t = 0; t < 6; ++t)
#pragma unroll
            for (int r = 0; r < 4; ++r) {
                const int o = (3 + t) * 16 + 4 * g + r;      // 48..143
                const int c = o - D_BINS;                    // -11..84
                if (c >= 0 && c < CTX)
                    sctx[m][c] = f2bf(acc[t][r] + bias[o]);
            }
        // coalesced writeout (wave-local LDS, ordered via lgkmcnt)
        const char* sb = (const char*)sctx;
        char* gb = (char*)ctx + ((size_t)(bn * PIXELS) + p0) * CTX * 2;
#pragma unroll
        for (int i = lane; i < PXT * CTX * 2 / 16; i += 64)   // 160 chunks
            *(float4*)(gb + i * 16) = *(const float4*)(sb + i * 16);
    }
}

// ---------------------------------------------------------------------------
// Kernel 2 (gather): EXACT r6 version (6 barriers; twice-verified-neutral,
// kept stable for a clean A/B on the gemm change).
// ---------------------------------------------------------------------------
__global__ __launch_bounds__(1024) void gather_kernel(
    const uint2* __restrict__ plist,
    const int*   __restrict__ cntmat_t,   // [NTILE][NBLK]
    const int*   __restrict__ ofsmat_t,   // [NTILE][NBLK]
    const unsigned short* __restrict__ ctx,
    float*       __restrict__ out)
{
    __shared__ float sacc[CTX][TCELLS + 1];   // 41.3 KB
    __shared__ uint2 bufB[CAPP];              // 29.7 KB
    __shared__ int segcnt[SEGS], segofsL[SEGS], segofsG[SEGS];
    __shared__ int cellcnt[TCELLS], celloff[TCELLS], cellcur[TCELLS];
    __shared__ int sTotal;
    uint2* bufA = (uint2*)sacc;               // overlay: bufA dead once sacc live

    const int tid    = threadIdx.x;
    const int wv     = tid >> 6;
    const int lane   = tid & 63;
    const int bucket = blockIdx.x;
    const int b      = bucket >> 7;
    const int tile   = bucket & 127;
    const int blk0   = b * SEGS;

    // phase 1: coalesced metadata loads + cellcnt zero
    if (tid < SEGS) {
        segcnt[tid]  = cntmat_t[(size_t)tile * NBLK + blk0 + tid];
        segofsG[tid] = ofsmat_t[(size_t)tile * NBLK + blk0 + tid];
    }
    if (tid >= 512 && tid < 512 + TCELLS) cellcnt[tid - 512] = 0;
    __syncthreads();

    // phase 2: wave 0 shfl-scans the 264 segment counts (5 chunks, carry)
    if (wv == 0) {
        int carry = 0;
#pragma unroll
        for (int c = 0; c < 5; ++c) {
            const int i = c * 64 + lane;
            const int v = (i < SEGS) ? segcnt[i] : 0;
            int incl = v;
#pragma unroll
            for (int off = 1; off < 64; off <<= 1) {
                const int t = __shfl_up(incl, off);
                if (lane >= off) incl += t;
            }
            if (i < SEGS) segofsL[i] = carry + incl - v;
            carry += __shfl(incl, 63);
        }
        if (lane == 0) sTotal = carry;
    }
    __syncthreads();
    const int total = sTotal;
    const int ncap  = (total < CAP) ? total : CAP;

    // phase 3: copy segments -> bufA AND build LDS cell histogram (fused)
    {
        const int sub = lane >> 3;
        const int sl  = lane & 7;
        for (int sgi = wv * 8 + sub; sgi < SEGS; sgi += 128) {
            const int n = segcnt[sgi];
            if (!n) continue;
            const int dstb = segofsL[sgi];
            const uint2* sp = plist + (size_t)(blk0 + sgi) * EPB + segofsG[sgi];
            for (int i = sl; i < n; i += 8) {
                const int d = dstb + i;
                if (d < CAP) {
                    const uint2 e = sp[i];
                    bufA[d] = e;
                    atomicAdd(&cellcnt[e.y & 127u], 1);
                }
            }
        }
    }
    __syncthreads();

    // phase 4: wave 1 shfl-scans the 128 PADDED cell counts
    if (wv == 1) {
        int carry = 0;
#pragma unroll
        for (int c = 0; c < 2; ++c) {
            const int i = c * 64 + lane;
            const int pv = (cellcnt[i] + 7) & ~7;
            int incl = pv;
#pragma unroll
            for (int off = 1; off < 64; off <<= 1) {
                const int t = __shfl_up(incl, off);
                if (lane >= off) incl += t;
            }
            celloff[i] = carry + incl - pv;
            cellcur[i] = 0;
            carry += __shfl(incl, 63);
        }
    }
    __syncthreads();

    // phase 5: zero pad slots (disjoint) + reorder bufA -> bufB cell-sorted
    if (tid < TCELLS) {
        const int o = celloff[tid] + cellcnt[tid];
        const int e = celloff[tid] + ((cellcnt[tid] + 7) & ~7);
        for (int i = o; i < e; ++i) bufB[i] = make_uint2(0u, 0u);
    }
    for (int i = tid; i < ncap; i += 1024) {
        const uint2 e = bufA[i];
        const int c = (int)(e.y & 127u);
        bufB[celloff[c] + atomicAdd(&cellcur[c], 1)] = e;
    }
    __syncthreads();   // bufA dead; sacc live from here

    // accumulate: wave wv owns cells c = wv, wv+16, ...; lane l<40 owns
    // channels (2l, 2l+1); 8-pt unrolled, one u32 (2xbf16) load per point.
    for (int c = wv; c < TCELLS; c += 16) {
        const int s0 = celloff[c];
        const int pc = (cellcnt[c] + 7) & ~7;
        float a0 = 0.f, a1 = 0.f;
        for (int i = 0; i < pc; i += 8) {
            uint2 e[8];
#pragma unroll
            for (int r = 0; r < 8; ++r) e[r] = bufB[s0 + i + r];
            if (lane < 40) {
                unsigned u[8];
#pragma unroll
                for (int r = 0; r < 8; ++r)
                    u[r] = *(const unsigned*)(ctx + (e[r].y >> 7) + 2 * lane);
#pragma unroll
                for (int r = 0; r < 8; ++r) {
                    const float d  = __uint_as_float(e[r].x);
                    a0 += d * __uint_as_float(u[r] << 16);
                    a1 += d * __uint_as_float(u[r] & 0xffff0000u);
                }
            }
        }
        if (lane < 40) {
            sacc[2 * lane][c]     = a0;
            sacc[2 * lane + 1][c] = a1;
        }
    }

    // slow path for bucket overflow (~30 sigma; correctness only)
    if (total > CAP) {
        for (int sgi = 0; sgi < SEGS; ++sgi) {
            const int dstb = segofsL[sgi];
            const int n    = segcnt[sgi];
            if (dstb + n <= CAP) continue;
            const uint2* sp = plist + (size_t)(blk0 + sgi) * EPB + segofsG[sgi];
            const int i0 = (CAP > dstb) ? (CAP - dstb) : 0;
            for (int i = i0; i < n; ++i) {
                const uint2 e = sp[i];
                const int c = (int)(e.y & 127u);
                if ((c & 15) == wv && lane < 40) {
                    const unsigned u = *(const unsigned*)(ctx + (e.y >> 7) + 2 * lane);
                    const float dep = __uint_as_float(e.x);
                    sacc[2 * lane][c]     += dep * __uint_as_float(u << 16);
                    sacc[2 * lane + 1][c] += dep * __uint_as_float(u & 0xffff0000u);
                }
            }
        }
    }
    __syncthreads();

    // epilogue: full 64B line writes to (B,C,H,W)
    const int tr = tile >> 3;
    const int tc = tile & 7;
    const int c0  = tid >> 4;
    const int col = tid & 15;
#pragma unroll
    for (int cc = c0; cc < CTX; cc += 64) {
#pragma unroll
        for (int r = 0; r < 8; ++r) {
            out[((size_t)(b * CTX + cc)) * BEVHW + (tr * 8 + r) * 128 + tc * 16 + col]
                = sacc[cc][r * 16 + col];
        }
    }
}

extern "C" void kernel_launch(void* const* d_in, const int* in_sizes, int n_in,
                              void* d_out, int out_size, void* d_ws, size_t ws_size,
                              hipStream_t stream)
{
    const float* img  = (const float*)d_in[0];
    const float* w    = (const float*)d_in[4];
    const float* bias = (const float*)d_in[5];
    const int*   geom = (const int*)d_in[6];
    float*       out  = (float*)d_out;

    float* ws = (float*)d_ws;
    unsigned short* wf   = (unsigned short*)(ws + WHLF_OFF);
    unsigned short* imgf = (unsigned short*)(ws + IMGF_OFF);
    __hip_bfloat16* ctx = (__hip_bfloat16*)(ws + CTX_OFF);
    int*   cntmat_t = (int*)(ws + CNTMAT_OFF);
    int*   ofsmat_t = (int*)(ws + OFSMAT_OFF);
    uint2* plist    = (uint2*)(ws + PLIST_OFF);

    // 0. fragment-major pre-conversion of W and img (one dispatch)
    {
        dim3 grid(NPXT + 1, BNPAIR);   // x<44: img slabs; x==44: W rows
        prep_kernel<<<grid, 256, 0, stream>>>(img, w, wf, imgf);
    }

    // 1. barrier-free one-wave MFMA blocks, fully-coalesced fragment loads
    {
        dim3 grid(NPXT, BNPAIR, 2);   // 2112 blocks x 64 threads
        gemm_fused<<<grid, 64, 0, stream>>>(imgf, wf, bias, geom, ctx,
                                            plist, cntmat_t, ofsmat_t);
    }

    // 2. 6-barrier gather (unchanged r6)
    gather_kernel<<<NBUCKET, 1024, 0, stream>>>(plist, cntmat_t, ofsmat_t,
                                                (const unsigned short*)ctx, out);
}

// Round 8
// 133.142 us; speedup vs baseline: 1.3033x; 1.0421x over previous
//
#include <hip/hip_runtime.h>
#include <hip/hip_bf16.h>
#include <math.h>

// Problem constants
#define D_BINS 59
#define CTX    80
#define O_TOT  139
#define K_CIN  256
#define PIXELS 704
#define BNPAIR 24
#define BEVHW  16384
#define NBATCH 4

// BEV binning: tile = 8 rows x 16 cols -> 128 cells, 128 tiles/batch.
#define NTILE   128
#define NBUCKET (NBATCH * NTILE)   // 512
#define TCELLS  128

// producer blocks: 16 px per 2-wave block; 24 bn * 44 ptiles.
#define PXT    16
#define NPXT   44                  // 704/16
#define NBLK   (BNPAIR * NPXT)     // 1056 regions
#define SEGS   (6 * NPXT)          // 264 segments per bucket
#define EPB    (PXT * D_BINS)      // 944 entries per region

#define CAP    2816
#define CAPP   (CAP + TCELLS * 5)  // 3456; pad-to-6 worst slack

// Workspace layout (4B units)
#define WHLF_OFF   0
#define WHLF_F     36864                           // W frags hi/lo, 147 KB
#define CTX_OFF    (WHLF_OFF + WHLF_F)
#define CTX_F      (BNPAIR * PIXELS * CTX / 2)     // 675,840
#define CNTMAT_OFF (CTX_OFF + CTX_F)               // transposed [NTILE][NBLK]
#define OFSMAT_OFF (CNTMAT_OFF + NTILE * NBLK)
#define PLIST_OFF  (OFSMAT_OFF + NTILE * NBLK)     // even -> uint2 aligned

typedef __attribute__((ext_vector_type(8))) short bf16x8;
typedef __attribute__((ext_vector_type(4))) float f32x4;

__device__ __forceinline__ unsigned short f2bf(float v) {
    __hip_bfloat16 h = __float2bfloat16(v);   // RNE
    return *reinterpret_cast<unsigned short*>(&h);
}
__device__ __forceinline__ float bf2f(unsigned short u) {
    return __uint_as_float(((unsigned)u) << 16);
}
__device__ __forceinline__ int pad6(int x) { return ((x + 5) / 6) * 6; }

// ---------------------------------------------------------------------------
// Kernel 0 (wsplit): W -> fragment-major bf16 hi/lo (r7 layout, verified):
// frag element (row=(t)*16+m, k=ks*32+g*8+e) at [(t*8+ks)*1024 + (g*16+m)*8+e],
// lo plane at +512.
// ---------------------------------------------------------------------------
__global__ __launch_bounds__(256) void wsplit_kernel(
    const float* __restrict__ w, unsigned short* __restrict__ wf)
{
    const int row = blockIdx.x;        // 0..143
    const int col = threadIdx.x;       // 0..255
    const float v = (row < O_TOT) ? w[(size_t)row * K_CIN + col] : 0.f;
    const unsigned short hi = f2bf(v);
    const unsigned short lo = f2bf(v - bf2f(hi));
    const int t = row >> 4, m = row & 15;
    const int ks = col >> 5, kk = col & 31;
    const int g = kk >> 3, e = kk & 7;
    const size_t base = (size_t)(t * 8 + ks) * 1024 + (g * 16 + m) * 8 + e;
    wf[base]       = hi;
    wf[base + 512] = lo;
}

// ---------------------------------------------------------------------------
// K-loop: B fragments from LDS (conflict-free ds_read_b128), A fragments from
// the L2-hot fragment-major W slab. Operand values + MFMA order bitwise
// identical to r7 (verified).
// ---------------------------------------------------------------------------
template<int NT, int T0>
__device__ __forceinline__ void kloopL(
    const unsigned short* __restrict__ bst,   // LDS [ks][pl][512]
    const unsigned short* __restrict__ wf,
    int lane, f32x4* acc)
{
#pragma unroll 2
    for (int ks = 0; ks < 8; ++ks) {
        const bf16x8 bhi = *(const bf16x8*)&bst[ks * 1024 + lane * 8];
        const bf16x8 blo = *(const bf16x8*)&bst[ks * 1024 + 512 + lane * 8];
#pragma unroll
        for (int t = 0; t < NT; ++t) {
            const size_t ab = (size_t)((T0 + t) * 8 + ks) * 1024 + lane * 8;
            const bf16x8 ahi = *(const bf16x8*)&wf[ab];
            const bf16x8 alo = *(const bf16x8*)&wf[ab + 512];
            acc[t] = __builtin_amdgcn_mfma_f32_16x16x32_bf16(ahi, bhi, acc[t], 0, 0, 0);
            acc[t] = __builtin_amdgcn_mfma_f32_16x16x32_bf16(ahi, blo, acc[t], 0, 0, 0);
            acc[t] = __builtin_amdgcn_mfma_f32_16x16x32_bf16(alo, bhi, acc[t], 0, 0, 0);
        }
    }
}

// ---------------------------------------------------------------------------
// Kernel 1: 2-wave blocks (wave 0 = depth rows 0..63, wave 1 = ctx rows
// 48..143). ONE __syncthreads: after the block stages its own 16px x 256k img
// tile to LDS as bf16 hi/lo fragments. Epilogues are wave-local (r7-exact).
// ---------------------------------------------------------------------------
__global__ __launch_bounds__(128) void gemm_fused(
    const float* __restrict__ img,            // (24, 256, 704)
    const unsigned short* __restrict__ wf,    // W frags
    const float* __restrict__ bias,           // (139)
    const int*   __restrict__ geom,           // (24, 59, 704, 2)
    __hip_bfloat16* __restrict__ ctx,         // (24, 704, 80) bf16
    uint2*       __restrict__ plist,          // [NBLK][EPB]
    int*         __restrict__ cntmat_t,       // [NTILE][NBLK]
    int*         __restrict__ ofsmat_t)       // [NTILE][NBLK]
{
    __shared__ unsigned short bst[8192];      // 16 KB [ks][pl][512]
    __shared__ int lh[NTILE], lofs[NTILE], lcur[NTILE];
    __shared__ unsigned short sctx[PXT][CTX]; // 2.5 KB

    const int tid  = threadIdx.x;
    const int lane = tid & 63;
    const int wv   = tid >> 6;                 // 0: depth, 1: ctx
    const int m    = lane & 15;
    const int g    = lane >> 4;                // == q for C-rows
    const int pt   = blockIdx.x;               // 0..43
    const int bn   = blockIdx.y;               // 0..23
    const int p0   = pt * PXT;
    const int pxg  = p0 + m;
    const int blkid = bn * NPXT + pt;

    // ---- stage img tile -> LDS fragments (coalesced float4 in) ----
    {
        const float* ib = img + (size_t)bn * K_CIN * PIXELS + p0;
        const int rb = tid >> 2, c4 = (tid & 3) * 4;
#pragma unroll
        for (int it = 0; it < 8; ++it) {
            const int row = rb + 32 * it;      // 0..255
            const float4 v = *(const float4*)&ib[(size_t)row * PIXELS + c4];
            const int ks = row >> 5, kk = row & 31;
            const int gg = kk >> 3, e = kk & 7;
            const int base = ks * 1024 + gg * 128 + e;
            const float a[4] = {v.x, v.y, v.z, v.w};
#pragma unroll
            for (int jj = 0; jj < 4; ++jj) {
                const int px = c4 + jj;
                const unsigned short hi = f2bf(a[jj]);
                bst[base + px * 8]       = hi;
                bst[base + px * 8 + 512] = f2bf(a[jj] - bf2f(hi));
            }
        }
    }
    lh[tid] = 0;
    lcur[tid] = 0;
    __syncthreads();   // the ONLY block barrier

    if (wv == 0) {
        // ================= depth role =================
        f32x4 acc[4];
#pragma unroll
        for (int t = 0; t < 4; ++t) acc[t] = (f32x4){0.f, 0.f, 0.f, 0.f};
        kloopL<4, 0>(bst, wf, lane, acc);

        // geom loads (latency overlaps softmax chain)
        const int2* g2 = (const int2*)geom;
        int2 gg[4][4];
#pragma unroll
        for (int t = 0; t < 4; ++t)
#pragma unroll
            for (int r = 0; r < 4; ++r) {
                const int o = 16 * t + 4 * g + r;
                if (o < D_BINS)
                    gg[t][r] = g2[((size_t)(bn * D_BINS + o)) * PIXELS + pxg];
            }

        // bias
#pragma unroll
        for (int t = 0; t < 4; ++t)
#pragma unroll
            for (int r = 0; r < 4; ++r) acc[t][r] += bias[16 * t + 4 * g + r];

        // softmax over o<59 (identical op order to verified kernels)
        float gm = -INFINITY;
#pragma unroll
        for (int t = 0; t < 4; ++t)
#pragma unroll
            for (int r = 0; r < 4; ++r)
                if (16 * t + 4 * g + r < D_BINS) gm = fmaxf(gm, acc[t][r]);
        gm = fmaxf(gm, __shfl_xor(gm, 16));
        gm = fmaxf(gm, __shfl_xor(gm, 32));
        float ls = 0.f;
#pragma unroll
        for (int t = 0; t < 4; ++t)
#pragma unroll
            for (int r = 0; r < 4; ++r)
                if (16 * t + 4 * g + r < D_BINS) {
                    const float e = __expf(acc[t][r] - gm);
                    acc[t][r] = e;
                    ls += e;
                }
        ls += __shfl_xor(ls, 16);
        ls += __shfl_xor(ls, 32);
        const float inv = 1.f / ls;

        // bucket/cell codes + wave-local histogram (LDS atomics, no barrier)
        unsigned uc[4][4];
#pragma unroll
        for (int t = 0; t < 4; ++t)
#pragma unroll
            for (int r = 0; r < 4; ++r) {
                const int o = 16 * t + 4 * g + r;
                if (o < D_BINS) {
                    const int2 q = gg[t][r];
                    const int tile = (q.x >> 3) * 8 + (q.y >> 4);
                    const int cell = (q.x & 7) * 16 + (q.y & 15);
                    uc[t][r] = (unsigned)((tile << 7) | cell);
                    atomicAdd(&lh[tile], 1);
                }
            }

        // in-wave scan of 128 tile counts: lane owns tiles 2l, 2l+1
        const int l2 = 2 * lane;
        const int a = lh[l2];
        const int b = lh[l2 + 1];
        const int p = a + b;
        int incl = p;
#pragma unroll
        for (int off = 1; off < 64; off <<= 1) {
            const int t = __shfl_up(incl, off);
            if (lane >= off) incl += t;
        }
        const int excl = incl - p;
        lofs[l2]     = excl;
        lofs[l2 + 1] = excl + a;
        cntmat_t[(size_t)l2 * NBLK + blkid]       = a;
        cntmat_t[(size_t)(l2 + 1) * NBLK + blkid] = b;
        ofsmat_t[(size_t)l2 * NBLK + blkid]       = excl;
        ofsmat_t[(size_t)(l2 + 1) * NBLK + blkid] = excl + a;

        // scatter this lane's own points
        uint2* dst = plist + (size_t)blkid * EPB;
        const unsigned ctxoff = (unsigned)((bn * PIXELS + pxg) * CTX);
#pragma unroll
        for (int t = 0; t < 4; ++t)
#pragma unroll
            for (int r = 0; r < 4; ++r) {
                const int o = 16 * t + 4 * g + r;
                if (o < D_BINS) {
                    const unsigned u = uc[t][r];
                    const int tl = (int)(u >> 7);
                    const int pos = lofs[tl] + atomicAdd(&lcur[tl], 1);
                    dst[pos] = make_uint2(__float_as_uint(acc[t][r] * inv),
                                          (ctxoff << 7) | (u & 127u));
                }
            }
    } else {
        // ================= ctx role =================
        f32x4 acc[6];
#pragma unroll
        for (int t = 0; t < 6; ++t) acc[t] = (f32x4){0.f, 0.f, 0.f, 0.f};
        kloopL<6, 3>(bst, wf, lane, acc);

#pragma unroll
        for (int t = 0; t < 6; ++t)
#pragma unroll
            for (int r = 0; r < 4; ++r) {
                const int o = (3 + t) * 16 + 4 * g + r;      // 48..143
                const int c = o - D_BINS;                    // -11..84
                if (c >= 0 && c < CTX)
                    sctx[m][c] = f2bf(acc[t][r] + bias[o]);
            }
        // coalesced writeout (wave-local LDS, ordered via lgkmcnt)
        const char* sb = (const char*)sctx;
        char* gb = (char*)ctx + ((size_t)(bn * PIXELS) + p0) * CTX * 2;
#pragma unroll
        for (int i = lane; i < PXT * CTX * 2 / 16; i += 64)   // 160 chunks
            *(float4*)(gb + i * 16) = *(const float4*)(sb + i * 16);
    }
}

// ---------------------------------------------------------------------------
// Kernel 2 (gather): r6/r7 phases 1-5 (6 barriers, fused copy+hist, shfl
// scans). NEW accumulate: 3 points per VMEM instr — lane<60: slot s=l/20,
// j=l%20 loads dwordx2 (channels 4j..4j+3, 480 B/wave-instr); cell-end
// reduce via 2 shfl, lanes<20 write sacc. Cell pad 8 -> 6.
// ---------------------------------------------------------------------------
__global__ __launch_bounds__(1024) void gather_kernel(
    const uint2* __restrict__ plist,
    const int*   __restrict__ cntmat_t,   // [NTILE][NBLK]
    const int*   __restrict__ ofsmat_t,   // [NTILE][NBLK]
    const unsigned short* __restrict__ ctx,
    float*       __restrict__ out)
{
    __shared__ float sacc[CTX][TCELLS + 1];   // 41.3 KB
    __shared__ uint2 bufB[CAPP];              // 27.6 KB
    __shared__ int segcnt[SEGS], segofsL[SEGS], segofsG[SEGS];
    __shared__ int cellcnt[TCELLS], celloff[TCELLS], cellcur[TCELLS];
    __shared__ int sTotal;
    uint2* bufA = (uint2*)sacc;               // overlay: bufA dead once sacc live

    const int tid    = threadIdx.x;
    const int wv     = tid >> 6;
    const int lane   = tid & 63;
    const int bucket = blockIdx.x;
    const int b      = bucket >> 7;
    const int tile   = bucket & 127;
    const int blk0   = b * SEGS;

    // phase 1: coalesced metadata loads + cellcnt zero
    if (tid < SEGS) {
        segcnt[tid]  = cntmat_t[(size_t)tile * NBLK + blk0 + tid];
        segofsG[tid] = ofsmat_t[(size_t)tile * NBLK + blk0 + tid];
    }
    if (tid >= 512 && tid < 512 + TCELLS) cellcnt[tid - 512] = 0;
    __syncthreads();

    // phase 2: wave 0 shfl-scans the 264 segment counts (5 chunks, carry)
    if (wv == 0) {
        int carry = 0;
#pragma unroll
        for (int c = 0; c < 5; ++c) {
            const int i = c * 64 + lane;
            const int v = (i < SEGS) ? segcnt[i] : 0;
            int incl = v;
#pragma unroll
            for (int off = 1; off < 64; off <<= 1) {
                const int t = __shfl_up(incl, off);
                if (lane >= off) incl += t;
            }
            if (i < SEGS) segofsL[i] = carry + incl - v;
            carry += __shfl(incl, 63);
        }
        if (lane == 0) sTotal = carry;
    }
    __syncthreads();
    const int total = sTotal;
    const int ncap  = (total < CAP) ? total : CAP;

    // phase 3: copy segments -> bufA AND build LDS cell histogram (fused)
    {
        const int sub = lane >> 3;
        const int sl  = lane & 7;
        for (int sgi = wv * 8 + sub; sgi < SEGS; sgi += 128) {
            const int n = segcnt[sgi];
            if (!n) continue;
            const int dstb = segofsL[sgi];
            const uint2* sp = plist + (size_t)(blk0 + sgi) * EPB + segofsG[sgi];
            for (int i = sl; i < n; i += 8) {
                const int d = dstb + i;
                if (d < CAP) {
                    const uint2 e = sp[i];
                    bufA[d] = e;
                    atomicAdd(&cellcnt[e.y & 127u], 1);
                }
            }
        }
    }
    __syncthreads();

    // phase 4: wave 1 shfl-scans the 128 cell counts padded to 6
    if (wv == 1) {
        int carry = 0;
#pragma unroll
        for (int c = 0; c < 2; ++c) {
            const int i = c * 64 + lane;
            const int pv = pad6(cellcnt[i]);
            int incl = pv;
#pragma unroll
            for (int off = 1; off < 64; off <<= 1) {
                const int t = __shfl_up(incl, off);
                if (lane >= off) incl += t;
            }
            celloff[i] = carry + incl - pv;
            cellcur[i] = 0;
            carry += __shfl(incl, 63);
        }
    }
    __syncthreads();

    // phase 5: zero pad slots (disjoint) + reorder bufA -> bufB cell-sorted
    if (tid < TCELLS) {
        const int o = celloff[tid] + cellcnt[tid];
        const int e = celloff[tid] + pad6(cellcnt[tid]);
        for (int i = o; i < e; ++i) bufB[i] = make_uint2(0u, 0u);
    }
    for (int i = tid; i < ncap; i += 1024) {
        const uint2 e = bufA[i];
        const int c = (int)(e.y & 127u);
        bufB[celloff[c] + atomicAdd(&cellcur[c], 1)] = e;
    }
    __syncthreads();   // bufA dead; sacc live from here

    // accumulate: wave wv owns cells c = wv, wv+16, ... (8 cells).
    // 3 points per chunk; lane<60: slot s=l/20, j=l%20 -> channels 4j..4j+3.
    {
        const int s  = lane / 20;           // 0..2 (3 for lanes 60-63, unused)
        const int j  = lane % 20;
        const unsigned* cx = (const unsigned*)ctx;
        for (int c = wv; c < TCELLS; c += 16) {
            const int s0 = celloff[c];
            const int pc = pad6(cellcnt[c]);
            float a0 = 0.f, a1 = 0.f, a2 = 0.f, a3 = 0.f;
            for (int i = 0; i < pc; i += 3) {
                uint2 es = make_uint2(0u, 0u);
                if (lane < 60) es = bufB[s0 + i + s];
                const uint2 u = *(const uint2*)&cx[(es.y >> 8) + 2 * j];
                const float dep = __uint_as_float(es.x);
                a0 += dep * __uint_as_float(u.x << 16);
                a1 += dep * __uint_as_float(u.x & 0xffff0000u);
                a2 += dep * __uint_as_float(u.y << 16);
                a3 += dep * __uint_as_float(u.y & 0xffff0000u);
            }
            // reduce across the 3 slots (originals, then sum)
            const float b0 = a0 + __shfl(a0, lane + 20) + __shfl(a0, lane + 40);
            const float b1 = a1 + __shfl(a1, lane + 20) + __shfl(a1, lane + 40);
            const float b2 = a2 + __shfl(a2, lane + 20) + __shfl(a2, lane + 40);
            const float b3 = a3 + __shfl(a3, lane + 20) + __shfl(a3, lane + 40);
            if (lane < 20) {
                sacc[4 * lane + 0][c] = b0;
                sacc[4 * lane + 1][c] = b1;
                sacc[4 * lane + 2][c] = b2;
                sacc[4 * lane + 3][c] = b3;
            }
        }
    }

    // slow path for bucket overflow (~30 sigma; correctness only)
    if (total > CAP) {
        for (int sgi = 0; sgi < SEGS; ++sgi) {
            const int dstb = segofsL[sgi];
            const int n    = segcnt[sgi];
            if (dstb + n <= CAP) continue;
            const uint2* sp = plist + (size_t)(blk0 + sgi) * EPB + segofsG[sgi];
            const int i0 = (CAP > dstb) ? (CAP - dstb) : 0;
            for (int i = i0; i < n; ++i) {
                const uint2 e = sp[i];
                const int c = (int)(e.y & 127u);
                if ((c & 15) == wv && lane < 40) {
                    const unsigned u = *(const unsigned*)(ctx + (e.y >> 7) + 2 * lane);
                    const float dep = __uint_as_float(e.x);
                    sacc[2 * lane][c]     += dep * __uint_as_float(u << 16);
                    sacc[2 * lane + 1][c] += dep * __uint_as_float(u & 0xffff0000u);
                }
            }
        }
    }
    __syncthreads();

    // epilogue: full 64B line writes to (B,C,H,W)
    const int tr = tile >> 3;
    const int tc = tile & 7;
    const int c0  = tid >> 4;
    const int col = tid & 15;
#pragma unroll
    for (int cc = c0; cc < CTX; cc += 64) {
#pragma unroll
        for (int r = 0; r < 8; ++r) {
            out[((size_t)(b * CTX + cc)) * BEVHW + (tr * 8 + r) * 128 + tc * 16 + col]
                = sacc[cc][r * 16 + col];
        }
    }
}

extern "C" void kernel_launch(void* const* d_in, const int* in_sizes, int n_in,
                              void* d_out, int out_size, void* d_ws, size_t ws_size,
                              hipStream_t stream)
{
    const float* img  = (const float*)d_in[0];
    const float* w    = (const float*)d_in[4];
    const float* bias = (const float*)d_in[5];
    const int*   geom = (const int*)d_in[6];
    float*       out  = (float*)d_out;

    float* ws = (float*)d_ws;
    unsigned short* wf = (unsigned short*)(ws + WHLF_OFF);
    __hip_bfloat16* ctx = (__hip_bfloat16*)(ws + CTX_OFF);
    int*   cntmat_t = (int*)(ws + CNTMAT_OFF);
    int*   ofsmat_t = (int*)(ws + OFSMAT_OFF);
    uint2* plist    = (uint2*)(ws + PLIST_OFF);

    // 0. W -> fragment-major bf16 hi/lo (147 KB, L2-resident)
    wsplit_kernel<<<144, 256, 0, stream>>>(w, wf);

    // 1. 2-wave blocks: LDS-staged B (1 barrier), wave0 depth / wave1 ctx
    {
        dim3 grid(NPXT, BNPAIR);   // 1056 blocks x 128 threads
        gemm_fused<<<grid, 128, 0, stream>>>(img, wf, bias, geom, ctx,
                                             plist, cntmat_t, ofsmat_t);
    }

    // 2. gather: 3-points-per-VMEM accumulate
    gather_kernel<<<NBUCKET, 1024, 0, stream>>>(plist, cntmat_t, ofsmat_t,
                                                (const unsigned short*)ctx, out);
}